// Round 1
// baseline (271.576 us; speedup 1.0000x reference)
//
#include <hip/hip_runtime.h>

// IndexNSW: batched greedy best-first NSW search.
// One workgroup per query (B=64 blocks, 512 threads). All per-query search
// state lives in LDS: visited/expanded bitmaps over N nodes, 32-slot pool.
// Semantics replicate the JAX reference exactly (stable top_k tie-breaking,
// per-node expanded/visited flags, duplicates-in-pool behavior).

#define DIMS     256
#define RDEG     32
#define EFPOOL   32
#define KOUT     10
#define NBITW    3125   // ceil(100000 / 32); N is read at runtime but fixed here
#define INF_D    1e30f

__global__ __launch_bounds__(512) void nsw_search_kernel(
    const float* __restrict__ query,    // [B, 256]
    const float* __restrict__ storage,  // [N, 256]
    const int*   __restrict__ graph,    // [N, 32]
    const int*   __restrict__ initial,  // [B, 32]
    float*       __restrict__ out,      // [B*10 ids as float][B*10 dists]
    int B)
{
    __shared__ unsigned int visited[NBITW];
    __shared__ unsigned int expanded[NBITW];
    __shared__ float pool_d[EFPOOL];
    __shared__ int   pool_id[EFPOOL];
    __shared__ float cand_d[RDEG];
    __shared__ int   cand_id[RDEG];
    __shared__ int   fresh_f[RDEG];
    __shared__ float all_d[2 * EFPOOL];
    __shared__ int   all_id[2 * EFPOOL];
    __shared__ float np_d[EFPOOL];
    __shared__ int   np_id[EFPOOL];
    __shared__ int   s_u;

    const int tid = threadIdx.x;
    const int b   = blockIdx.x;
    const int g   = tid >> 4;   // neighbor group 0..31
    const int l   = tid & 15;   // lane within group (16-dim slice owner)

    // ---- zero bitmaps ----
    for (int i = tid; i < NBITW; i += 512) { visited[i] = 0u; expanded[i] = 0u; }

    // ---- per-lane query slice in registers (64B-aligned float4 loads) ----
    float qv[16];
    {
        const float4* qp4 = reinterpret_cast<const float4*>(query + (size_t)b * DIMS + l * 16);
        #pragma unroll
        for (int j = 0; j < 4; ++j) {
            float4 v = qp4[j];
            qv[4*j+0] = v.x; qv[4*j+1] = v.y; qv[4*j+2] = v.z; qv[4*j+3] = v.w;
        }
    }

    // ---- initial candidates: ids + visited bits ----
    if (tid < EFPOOL) {
        int id = initial[b * EFPOOL + tid];
        cand_id[tid] = id;
        atomicOr(&visited[id >> 5], 1u << (id & 31));
    }
    __syncthreads();

    // ---- initial pool distances ----
    {
        int id = cand_id[g];
        const float4* sp4 = reinterpret_cast<const float4*>(storage + (size_t)id * DIMS + l * 16);
        float acc = 0.f;
        #pragma unroll
        for (int j = 0; j < 4; ++j) {
            float4 s4 = sp4[j];
            float d0 = s4.x - qv[4*j+0]; acc = fmaf(d0, d0, acc);
            float d1 = s4.y - qv[4*j+1]; acc = fmaf(d1, d1, acc);
            float d2 = s4.z - qv[4*j+2]; acc = fmaf(d2, d2, acc);
            float d3 = s4.w - qv[4*j+3]; acc = fmaf(d3, d3, acc);
        }
        #pragma unroll
        for (int m = 1; m < 16; m <<= 1) acc += __shfl_xor(acc, m, 64);
        if (l == 0) { pool_d[g] = acc; pool_id[g] = id; }
    }
    __syncthreads();

    // ---- ef_search expansion steps ----
    for (int step = 0; step < EFPOOL; ++step) {
        // 1) pick closest unexpanded candidate (argmin with index tie-break)
        if (tid < 32) {
            int   id = pool_id[tid];
            bool  ex = (expanded[id >> 5] >> (id & 31)) & 1u;
            float pd = ex ? INF_D : pool_d[tid];
            int   ix = tid;
            #pragma unroll
            for (int m = 16; m >= 1; m >>= 1) {
                float od = __shfl_xor(pd, m, 64);
                int   oi = __shfl_xor(ix, m, 64);
                if (od < pd || (od == pd && oi < ix)) { pd = od; ix = oi; }
            }
            if (tid == 0) {
                int u = pool_id[ix];
                s_u = u;
                expanded[u >> 5] |= (1u << (u & 31));   // sole writer
            }
        }
        __syncthreads();
        const int u = s_u;

        // 2) gather neighbors; fresh = !visited (pre-update, all-before-any)
        if (tid < RDEG) {
            int nb = graph[(size_t)u * RDEG + tid];
            cand_id[tid] = nb;
            fresh_f[tid] = !((visited[nb >> 5] >> (nb & 31)) & 1u);
        }
        __syncthreads();
        if (tid < RDEG) {
            int nb = cand_id[tid];
            if (fresh_f[tid]) atomicOr(&visited[nb >> 5], 1u << (nb & 31));
        }

        // 3) distances for fresh neighbors (group g -> neighbor g)
        {
            int  f  = fresh_f[g];
            int  id = cand_id[g];
            float acc = 0.f;
            if (f) {
                const float4* sp4 = reinterpret_cast<const float4*>(storage + (size_t)id * DIMS + l * 16);
                #pragma unroll
                for (int j = 0; j < 4; ++j) {
                    float4 s4 = sp4[j];
                    float d0 = s4.x - qv[4*j+0]; acc = fmaf(d0, d0, acc);
                    float d1 = s4.y - qv[4*j+1]; acc = fmaf(d1, d1, acc);
                    float d2 = s4.z - qv[4*j+2]; acc = fmaf(d2, d2, acc);
                    float d3 = s4.w - qv[4*j+3]; acc = fmaf(d3, d3, acc);
                }
            }
            #pragma unroll
            for (int m = 1; m < 16; m <<= 1) acc += __shfl_xor(acc, m, 64);
            if (l == 0) cand_d[g] = f ? acc : INF_D;
        }
        __syncthreads();

        // 4) stable top-32 merge == lax.top_k(-all_d, 32) semantics.
        //    rank_i = #{j : (d_j, j) < (d_i, i)}  -> strict total order.
        if (tid < 64) {
            if (tid < 32) { all_d[tid] = pool_d[tid]; all_id[tid] = pool_id[tid]; }
            else          { all_d[tid] = cand_d[tid - 32]; all_id[tid] = cand_id[tid - 32]; }
        }
        __syncthreads();
        if (tid < 64) {
            float di = all_d[tid];
            int rank = 0;
            #pragma unroll 8
            for (int j = 0; j < 64; ++j) {
                float dj = all_d[j];
                rank += (dj < di || (dj == di && j < tid)) ? 1 : 0;
            }
            if (rank < 32) { np_d[rank] = di; np_id[rank] = all_id[tid]; }
        }
        __syncthreads();
        if (tid < 32) { pool_d[tid] = np_d[tid]; pool_id[tid] = np_id[tid]; }
        __syncthreads();
    }

    // ---- output: pool is top_k-sorted ascending; first 10 slots are the answer.
    // ids written as float (exact below 2^24), then dists, concatenated flat.
    if (tid < KOUT) {
        out[b * KOUT + tid]              = (float)pool_id[tid];
        out[B * KOUT + b * KOUT + tid]   = pool_d[tid];
    }
}

extern "C" void kernel_launch(void* const* d_in, const int* in_sizes, int n_in,
                              void* d_out, int out_size, void* d_ws, size_t ws_size,
                              hipStream_t stream) {
    const float* query   = (const float*)d_in[0];
    const float* storage = (const float*)d_in[1];
    const int*   graph   = (const int*)d_in[2];
    const int*   initial = (const int*)d_in[3];
    // d_in[4] = k (10), d_in[5] = ef_search (32): fixed by setup, hardcoded.
    float* out = (float*)d_out;

    const int B = in_sizes[0] / DIMS;   // 64

    nsw_search_kernel<<<B, 512, 0, stream>>>(query, storage, graph, initial, out, B);
}